// Round 16
// baseline (421.862 us; speedup 1.0000x reference)
//
#include <hip/hip_runtime.h>
#include <math.h>

// Problem constants
#define BB 2
#define NDIM 64      // D = H = W = 64
#define CC 128       // channels
#define WR 33        // rfft bins along W
#define NBLK 8
#define BSZ 16

static constexpr float LAM = 0.01f;            // softshrink lambda
static constexpr float ORTHO = 1.0f / 512.0f;  // 1/sqrt(64^3)
static constexpr float TWO_PI_64 = 6.28318530717958647692f / 64.0f;
// Residual spectrum scale: iW_sum misses the H,D round-trip factors (64*64);
// iW_Sigma(Z*4096)*ORTHO == x exactly (in exact arithmetic).
static constexpr float XSCALE = 4096.0f;

// LDS row stride (in float2) for one 64-elem transform.
// Bank analysis (32 banks, b64 ops -> bank = word%32, 2 words/elem):
//   pitch 65: staging 2-way, FFT stage-1 8-way  (r15: REGRESSED, 417us)
//   pitch 66: staging 4-way, FFT 4-way          (r13: 383us)
//   pitch 67: staging 2-way (free), FFT 4-way   -> strictly dominates 66
#define LROW 67

// Spectrum element strides (uint32 units), layout (b, d, h, wr, c)
#define S_WRs 128L
#define S_Hs 4224L      // 33*128
#define S_Ds 270336L    // 64*4224
#define S_Bs 17301504L  // 64*270336
// Workspace tail (u32 units): weight fragments + biases + residual spectrum
#define WS_FRAG_OFF 34603008L
#define WS_BIAS_OFF (WS_FRAG_OFF + 8192L)
#define WS_BUFX_OFF (WS_BIAS_OFF + 512L)   // second 138.4 MB spectrum (bufX)

typedef short bf16x8 __attribute__((ext_vector_type(8)));
typedef float f32x4v __attribute__((ext_vector_type(4)));
typedef float f32x2n __attribute__((ext_vector_type(2)));     // NT-capable f32x2
typedef unsigned u32x2n __attribute__((ext_vector_type(2)));  // NT-capable u32x2

__device__ inline float2 cmulf(float2 a, float2 b) {
    return make_float2(a.x * b.x - a.y * b.y, a.x * b.y + a.y * b.x);
}
__device__ inline float2 cadd(float2 a, float2 b) { return make_float2(a.x + b.x, a.y + b.y); }
__device__ inline float2 csub(float2 a, float2 b) { return make_float2(a.x - b.x, a.y - b.y); }

// bf16 pair pack via HW cvt (RNE): D[15:0]=bf16(x), D[31:16]=bf16(y).
__device__ inline unsigned pack_c(float2 v) {
    unsigned r;
    asm("v_cvt_pk_bf16_f32 %0, %1, %2" : "=v"(r) : "v"(v.x), "v"(v.y));
    return r;
}
__device__ inline float2 unpack_c(unsigned u) {
    return make_float2(__uint_as_float(u << 16), __uint_as_float(u & 0xffff0000u));
}

// Fast 8-point DFT, radix-2 DIT. DIR = -1 forward, +1 inverse. ~56 real ops.
template <int DIR>
__device__ inline float2 jmul(float2 z) {  // DIR*i * z
    return (DIR < 0) ? make_float2(z.y, -z.x) : make_float2(-z.y, z.x);
}
template <int DIR>
__device__ inline void dft8(const float2 v[8], float2 y[8]) {
    const float s = 0.70710678118654752440f;
    float2 a0 = cadd(v[0], v[4]), a1 = csub(v[0], v[4]);
    float2 a2 = cadd(v[2], v[6]), a3 = csub(v[2], v[6]);
    float2 A0 = cadd(a0, a2), A2 = csub(a0, a2);
    float2 tj = jmul<DIR>(a3);
    float2 A1 = cadd(a1, tj), A3 = csub(a1, tj);
    float2 b0 = cadd(v[1], v[5]), b1 = csub(v[1], v[5]);
    float2 b2 = cadd(v[3], v[7]), b3 = csub(v[3], v[7]);
    float2 B0 = cadd(b0, b2), B2 = csub(b0, b2);
    float2 uj = jmul<DIR>(b3);
    float2 B1 = cadd(b1, uj), B3 = csub(b1, uj);
    float2 W1B1 = (DIR < 0) ? make_float2(s * (B1.x + B1.y), s * (B1.y - B1.x))
                            : make_float2(s * (B1.x - B1.y), s * (B1.x + B1.y));
    float2 W2B2 = jmul<DIR>(B2);
    float2 W3B3 = (DIR < 0) ? make_float2(s * (B3.y - B3.x), -s * (B3.x + B3.y))
                            : make_float2(-s * (B3.x + B3.y), s * (B3.x - B3.y));
    y[0] = cadd(A0, B0);   y[4] = csub(A0, B0);
    y[1] = cadd(A1, W1B1); y[5] = csub(A1, W1B1);
    y[2] = cadd(A2, W2B2); y[6] = csub(A2, W2B2);
    y[3] = cadd(A3, W3B3); y[7] = csub(A3, W3B3);
}

// Per-thread twiddles for its p = t&7: tw[k1-1] = (cos, sin)(+2*pi*p*k1/64)
__device__ inline void make_tw(int p, float2 tw[7]) {
#pragma unroll
    for (int k1 = 1; k1 < 8; k1++) {
        float ang = TWO_PI_64 * (float)(p * k1);
        float sn, cs;
        __sincosf(ang, &sn, &cs);
        tw[k1 - 1] = make_float2(cs, sn);
    }
}

// 64-pt FFT on 64 contiguous float2 in LDS, cooperatively by 8 threads p=0..7
// (lanes 8r..8r+7 of ONE wave: wave-synchronous, no block barriers).
template <int DIR>
__device__ inline void fft64_lds(float2* base, int p, const float2 tw[7]) {
    float2 v[8], a[8];
#pragma unroll
    for (int n1 = 0; n1 < 8; n1++) v[n1] = base[8 * n1 + p];
    dft8<DIR>(v, a);
#pragma unroll
    for (int k1 = 1; k1 < 8; k1++) {
        float2 w = make_float2(tw[k1 - 1].x, (float)DIR * tw[k1 - 1].y);
        a[k1] = cmulf(a[k1], w);
    }
#pragma unroll
    for (int k1 = 0; k1 < 8; k1++) base[8 * k1 + p] = a[k1];
    __builtin_amdgcn_wave_barrier();
    float2 u[8], y[8];
#pragma unroll
    for (int n2 = 0; n2 < 8; n2++) u[n2] = base[8 * p + n2];
    dft8<DIR>(u, y);
    __builtin_amdgcn_wave_barrier();
#pragma unroll
    for (int k2 = 0; k2 < 8; k2++) base[8 * k2 + p] = y[k2];
}

// ---------------- Setup: build MFMA weight fragments + biases into d_ws tail.
__global__ __launch_bounds__(256) void k_wfrag(const float* __restrict__ w1,
                                               const float* __restrict__ b1,
                                               const float* __restrict__ w2,
                                               const float* __restrict__ b2,
                                               uint4* __restrict__ WFg,
                                               float* __restrict__ BIASg) {
    const int t = threadIdx.x;
    const int widx = blockIdx.x * 256 + t;  // 0..2047
    const int lane = widx & 63;
    const int half = (widx >> 6) & 1;   // 0: real-out cols, 1: imag-out cols
    const float* ws = (widx & 128) ? w2 : w1;
    const int blk = widx >> 8;
    const int n = lane & 15;
    const int kc = lane >> 4;
    unsigned wrd[4];
#pragma unroll
    for (int j2 = 0; j2 < 4; j2++) {
        float v[2];
#pragma unroll
        for (int e = 0; e < 2; e++) {
            const int k = kc * 8 + j2 * 2 + e;
            float val;
            if (k < 16)
                val = half ? ws[2048 + blk * 256 + k * 16 + n]
                           : ws[blk * 256 + k * 16 + n];
            else
                val = half ? ws[blk * 256 + (k - 16) * 16 + n]
                           : -ws[2048 + blk * 256 + (k - 16) * 16 + n];
            v[e] = val;
        }
        wrd[j2] = pack_c(make_float2(v[0], v[1]));
    }
    WFg[widx] = make_uint4(wrd[0], wrd[1], wrd[2], wrd[3]);
    if (blockIdx.x == 0) {
        BIASg[t] = b1[t];
        BIASg[256 + t] = b2[t];
    }
}

// ---------------- Pass 1: rfft along W, two real channels packed per complex
// FFT. x f32 -> buf (b,d,h,wr,c) packed bf16, + bufX = spectrum*4096 (NT) for
// the residual path (pass 5 reconstructs x from it; no second x read).
__global__ __launch_bounds__(256) void k_rfft_w(const float* __restrict__ x,
                                                unsigned* __restrict__ buf,
                                                unsigned* __restrict__ bufX) {
    __shared__ float2 lds[32 * LROW];
    const int t = threadIdx.x;
    const size_t bdh = blockIdx.x;
    const float* xp = x + bdh * (size_t)(NDIM * CC);
    unsigned* op = buf + bdh * (size_t)(WR * CC);
    unsigned* opX = bufX + bdh * (size_t)(WR * CC);
    float2 tw[7];
    make_tw(t & 7, tw);
    for (int chunk = 0; chunk < 2; chunk++) {
        const int c0 = chunk * 64;  // 32 channel-pairs per chunk
#pragma unroll
        for (int k8 = 0; k8 < 8; k8++) {
            int idx = k8 * 256 + t;
            int p = idx & 31, w = idx >> 5;
            f32x2n v = __builtin_nontemporal_load(
                (const f32x2n*)&xp[(size_t)w * CC + c0 + 2 * p]);
            lds[p * LROW + w] = make_float2(v.x * ORTHO, v.y * ORTHO);
        }
        __syncthreads();
        fft64_lds<-1>(&lds[(t >> 3) * LROW], t & 7, tw);
        __syncthreads();
        // untangle: Xa = (Z[k]+conj(Z[m]))/2, Xb = -i(Z[k]-conj(Z[m]))/2, m=64-k
        for (int i = t; i < WR * 32; i += 256) {
            int p = i & 31, k = i >> 5;
            int m = (64 - k) & 63;
            float2 Z1 = lds[p * LROW + k];
            float2 Z2 = lds[p * LROW + m];
            float2 Xa = make_float2(0.5f * (Z1.x + Z2.x), 0.5f * (Z1.y - Z2.y));
            float2 Xb = make_float2(0.5f * (Z1.y + Z2.y), 0.5f * (Z2.x - Z1.x));
            size_t oi = (size_t)k * CC + c0 + 2 * p;
            uint2 u = make_uint2(pack_c(Xa), pack_c(Xb));
            *(uint2*)&op[oi] = u;
            u32x2n ux;
            ux.x = pack_c(make_float2(Xa.x * XSCALE, Xa.y * XSCALE));
            ux.y = pack_c(make_float2(Xb.x * XSCALE, Xb.y * XSCALE));
            __builtin_nontemporal_store(ux, (u32x2n*)&opX[oi]);
        }
        __syncthreads();
    }
}

// ---------------- Passes 2,4: in-place complex FFT along H (coalesced staging).
template <int DIR>
__global__ __launch_bounds__(256) void k_fft_axis(unsigned* __restrict__ buf, int outerB,
                                                  long sA, long sB, long sAxis) {
    __shared__ float2 lds[32 * LROW];
    const int t = threadIdx.x;
    const long a = blockIdx.x / outerB;
    const long ob = blockIdx.x % outerB;
    unsigned* p0 = buf + a * sA + ob * sB;
    float2 tw[7];
    make_tw(t & 7, tw);
    for (int chunk = 0; chunk < 4; chunk++) {
        const int c0 = chunk * 32;
#pragma unroll
        for (int k = 0; k < 8; k++) {
            int i = k * 256 + t;
            int c = i & 31, n = i >> 5;
            lds[c * LROW + n] = unpack_c(p0[(long)n * sAxis + c0 + c]);
        }
        __syncthreads();
        fft64_lds<DIR>(&lds[(t >> 3) * LROW], t & 7, tw);
        __syncthreads();
#pragma unroll
        for (int k = 0; k < 8; k++) {
            int i = k * 256 + t;
            int c = i & 31, n = i >> 5;
            p0[(long)n * sAxis + c0 + c] = pack_c(lds[c * LROW + n]);
        }
        __syncthreads();
    }
}

// ---------------- Pass 3 (fused): FFT-D -> MFMA MLP + softshrink -> iFFT-D.
// CTA per (b,h,wr); 4 chunks of [d=64][32 ch] (= 2 MLP blocks each) in f32 LDS.
// Wave wv owns point-columns wv*16..+15 in the MLP phase (reads AND writes) so
// no cross-wave hazard there; FFT phases sync via __syncthreads.
__global__ __launch_bounds__(256) void k_dmlp3(unsigned* __restrict__ buf,
                                               const uint4* __restrict__ WFg,
                                               const float* __restrict__ BIASg) {
    __shared__ float2 lds[32 * LROW];   // 17.2 KB
    __shared__ unsigned SHUF[4 * 272];  // 4.3 KB
    __shared__ float BIAS[512];         // 2 KB
    const int t = threadIdx.x;
    int id = blockIdx.x;
    const int wr = id % WR; id /= WR;
    const int h = id % NDIM; id /= NDIM;
    const int b = id;
    unsigned* p0 = buf + (long)b * S_Bs + (long)h * S_Hs + (long)wr * S_WRs;
    BIAS[t] = BIASg[t];
    BIAS[256 + t] = BIASg[256 + t];
    float2 tw[7];
    make_tw(t & 7, tw);
    const int wv = t >> 6, l = t & 63;
    const int m = l & 15;
    const int kc = l >> 4;
    const int c0m = (kc & 1) * 8;
    const bool imh = kc >= 2;
    unsigned* shuf = &SHUF[wv * 272];

#pragma unroll 1
    for (int ck = 0; ck < 4; ck++) {
        const int c0 = ck * 32;
        // stage (coalesced)
#pragma unroll
        for (int k = 0; k < 8; k++) {
            int i = k * 256 + t;
            int c = i & 31, n = i >> 5;
            lds[c * LROW + n] = unpack_c(p0[(long)n * S_Ds + c0 + c]);
        }
        __syncthreads();
        // forward FFT along d (rows = channels, wave-synchronous)
        fft64_lds<-1>(&lds[(t >> 3) * LROW], t & 7, tw);
        __syncthreads();
        // MFMA MLP on the tile: 2 blocks in this chunk
#pragma unroll 1
        for (int bq = 0; bq < 2; bq++) {
            const int blk = ck * 2 + bq;
            union { unsigned w[4]; bf16x8 v; } A;
#pragma unroll
            for (int j2 = 0; j2 < 4; j2++) {
                float2 va = lds[(bq * 16 + c0m + 2 * j2) * LROW + wv * 16 + m];
                float2 vb = lds[(bq * 16 + c0m + 2 * j2 + 1) * LROW + wv * 16 + m];
                A.w[j2] = imh ? pack_c(make_float2(va.y, vb.y))
                              : pack_c(make_float2(va.x, vb.x));
            }
            union { uint4 q; bf16x8 v; } B1r, B1i, B2r, B2i;
            B1r.q = WFg[(blk * 4 + 0) * 64 + l];
            B1i.q = WFg[(blk * 4 + 1) * 64 + l];
            f32x4v Dr = {0.f, 0.f, 0.f, 0.f}, Di = {0.f, 0.f, 0.f, 0.f};
            Dr = __builtin_amdgcn_mfma_f32_16x16x32_bf16(A.v, B1r.v, Dr, 0, 0, 0);
            Di = __builtin_amdgcn_mfma_f32_16x16x32_bf16(A.v, B1i.v, Di, 0, 0, 0);
            const float b1r_ = BIAS[blk * 16 + m];
            const float b1i_ = BIAS[128 + blk * 16 + m];
#pragma unroll
            for (int r = 0; r < 4; r++) {
                const float o1r = fmaxf(Dr[r] + b1r_, 0.f);
                const float o1i = fmaxf(Di[r] + b1i_, 0.f);
                shuf[(kc * 4 + r) * 17 + m] = pack_c(make_float2(o1r, o1i));
            }
            __builtin_amdgcn_wave_barrier();
            unsigned s[8];
#pragma unroll
            for (int j = 0; j < 8; j++) s[j] = shuf[m * 17 + c0m + j];
            __builtin_amdgcn_wave_barrier();
            union { unsigned w[4]; bf16x8 v; } A2;
            if (!imh) {
                A2.w[0] = (s[0] & 0xffffu) | (s[1] << 16);
                A2.w[1] = (s[2] & 0xffffu) | (s[3] << 16);
                A2.w[2] = (s[4] & 0xffffu) | (s[5] << 16);
                A2.w[3] = (s[6] & 0xffffu) | (s[7] << 16);
            } else {
                A2.w[0] = (s[0] >> 16) | (s[1] & 0xffff0000u);
                A2.w[1] = (s[2] >> 16) | (s[3] & 0xffff0000u);
                A2.w[2] = (s[4] >> 16) | (s[5] & 0xffff0000u);
                A2.w[3] = (s[6] >> 16) | (s[7] & 0xffff0000u);
            }
            B2r.q = WFg[(blk * 4 + 2) * 64 + l];
            B2i.q = WFg[(blk * 4 + 3) * 64 + l];
            f32x4v Er = {0.f, 0.f, 0.f, 0.f}, Ei = {0.f, 0.f, 0.f, 0.f};
            Er = __builtin_amdgcn_mfma_f32_16x16x32_bf16(A2.v, B2r.v, Er, 0, 0, 0);
            Ei = __builtin_amdgcn_mfma_f32_16x16x32_bf16(A2.v, B2i.v, Ei, 0, 0, 0);
            const float b2r_ = BIAS[256 + blk * 16 + m];
            const float b2i_ = BIAS[384 + blk * 16 + m];
#pragma unroll
            for (int r = 0; r < 4; r++) {
                float sr = Er[r] + b2r_, si = Ei[r] + b2i_;
                sr = (sr > LAM) ? (sr - LAM) : ((sr < -LAM) ? (sr + LAM) : 0.f);
                si = (si > LAM) ? (si - LAM) : ((si < -LAM) ? (si + LAM) : 0.f);
                lds[(bq * 16 + m) * LROW + wv * 16 + kc * 4 + r] =
                    make_float2(sr, si);
            }
            __builtin_amdgcn_wave_barrier();
        }
        __syncthreads();
        // inverse FFT along d
        fft64_lds<1>(&lds[(t >> 3) * LROW], t & 7, tw);
        __syncthreads();
        // store (coalesced, packed)
#pragma unroll
        for (int k = 0; k < 8; k++) {
            int i = k * 256 + t;
            int c = i & 31, n = i >> 5;
            p0[(long)n * S_Ds + c0 + c] = pack_c(lds[c * LROW + n]);
        }
        __syncthreads();
    }
}

// ---------------- Pass 5: irfft along W + residual-from-spectrum. Adds the
// pass-1-saved x-spectrum (bufX, NT) to the MLP spectrum before the inverse
// transform — no second read of x. Out stores NT.
__global__ __launch_bounds__(256) void k_irfft_w(const unsigned* __restrict__ buf,
                                                 const unsigned* __restrict__ bufX,
                                                 float* __restrict__ out) {
    __shared__ float2 lds[32 * LROW];
    const int t = threadIdx.x;
    const size_t bdh = blockIdx.x;
    const unsigned* ip = buf + bdh * (size_t)(WR * CC);
    const unsigned* ipX = bufX + bdh * (size_t)(WR * CC);
    float* op = out + bdh * (size_t)(NDIM * CC);
    float2 tw[7];
    make_tw(t & 7, tw);
    for (int chunk = 0; chunk < 2; chunk++) {
        const int c0 = chunk * 64;
        for (int i = t; i < WR * 32; i += 256) {
            int p = i & 31, k = i >> 5;
            size_t ii = (size_t)k * CC + c0 + 2 * p;
            uint2 u = *(const uint2*)&ip[ii];
            u32x2n uX = __builtin_nontemporal_load((const u32x2n*)&ipX[ii]);
            float2 Xa = unpack_c(u.x), XaX = unpack_c(uX.x);
            float2 Xb = unpack_c(u.y), XbX = unpack_c(uX.y);
            Xa.x += XaX.x; Xa.y += XaX.y;
            Xb.x += XbX.x; Xb.y += XbX.y;
            if (k == 0 || k == 32) { Xa.y = 0.f; Xb.y = 0.f; }
            lds[p * LROW + k] = make_float2(Xa.x - Xb.y, Xa.y + Xb.x);
            if (k >= 1 && k <= 31)
                lds[p * LROW + (64 - k)] = make_float2(Xa.x + Xb.y, Xb.x - Xa.y);
        }
        __syncthreads();
        fft64_lds<1>(&lds[(t >> 3) * LROW], t & 7, tw);
        __syncthreads();
#pragma unroll
        for (int k8 = 0; k8 < 8; k8++) {
            int idx = k8 * 256 + t;
            int p = idx & 31, w = idx >> 5;
            float2 z = lds[p * LROW + w];
            size_t gi = (size_t)w * CC + c0 + 2 * p;
            f32x2n o;
            o.x = z.x * ORTHO;
            o.y = z.y * ORTHO;
            __builtin_nontemporal_store(o, (f32x2n*)&op[gi]);
        }
        __syncthreads();
    }
}

extern "C" void kernel_launch(void* const* d_in, const int* in_sizes, int n_in,
                              void* d_out, int out_size, void* d_ws, size_t ws_size,
                              hipStream_t stream) {
    const float* x = (const float*)d_in[0];
    const float* w1 = (const float*)d_in[1];
    const float* b1 = (const float*)d_in[2];
    const float* w2 = (const float*)d_in[3];
    const float* b2 = (const float*)d_in[4];
    float* out = (float*)d_out;
    unsigned* buf = (unsigned*)d_ws;  // 138.4 MB spectrum (L3-resident)
    uint4* WFg = (uint4*)(buf + WS_FRAG_OFF);
    float* BIASg = (float*)(buf + WS_BIAS_OFF);
    unsigned* bufX = buf + WS_BUFX_OFF;  // 138.4 MB residual spectrum (NT)

    // 0) build MFMA weight fragments + biases (32 KB + 2 KB in d_ws tail)
    k_wfrag<<<8, 256, 0, stream>>>(w1, b1, w2, b2, WFg, BIASg);
    // 1) rfft along W (channel-pair packed, NT x-loads; writes buf + bufX)
    k_rfft_w<<<BB * NDIM * NDIM, 256, 0, stream>>>(x, buf, bufX);
    // 2) FFT along H: per (b,d,wr)
    k_fft_axis<-1><<<BB * NDIM * WR, 256, 0, stream>>>(buf, WR, S_Ds, S_WRs, S_Hs);
    // 3) fused FFT-D -> MFMA MLP + softshrink -> iFFT-D: per (b,h,wr)
    k_dmlp3<<<BB * NDIM * WR, 256, 0, stream>>>(buf, WFg, BIASg);
    // 4) inverse FFT along H
    k_fft_axis<1><<<BB * NDIM * WR, 256, 0, stream>>>(buf, WR, S_Ds, S_WRs, S_Hs);
    // 5) irfft along W + residual from bufX (no x re-read)
    k_irfft_w<<<BB * NDIM * NDIM, 256, 0, stream>>>(buf, bufX, out);
}

// Round 17
// 379.398 us; speedup vs baseline: 1.1119x; 1.1119x over previous
//
#include <hip/hip_runtime.h>
#include <math.h>

// Problem constants
#define BB 2
#define NDIM 64      // D = H = W = 64
#define CC 128       // channels
#define WR 33        // rfft bins along W
#define NBLK 8
#define BSZ 16

static constexpr float LAM = 0.01f;            // softshrink lambda
static constexpr float ORTHO = 1.0f / 512.0f;  // 1/sqrt(64^3)
static constexpr float TWO_PI_64 = 6.28318530717958647692f / 64.0f;

// LDS row stride (in float2) for one 64-elem transform: 66.
// NOTE (r15/r16): odd pitches (65, 67) regress ~9% — odd float2 pitch makes
// half the rows 4B-aligned for b64 LDS ops (misaligned split) which costs
// more than the 4-way bank conflicts saved. 66 is optimal among even pitches.
#define LROW 66

// Spectrum element strides (uint32 units), layout (b, d, h, wr, c)
#define S_WRs 128L
#define S_Hs 4224L      // 33*128
#define S_Ds 270336L    // 64*4224
#define S_Bs 17301504L  // 64*270336
// Workspace tail (u32 units): weight fragments + biases after the 138.4MB buf
#define WS_FRAG_OFF 34603008L
#define WS_BIAS_OFF (WS_FRAG_OFF + 8192L)

typedef short bf16x8 __attribute__((ext_vector_type(8)));
typedef float f32x4v __attribute__((ext_vector_type(4)));
typedef float f32x2n __attribute__((ext_vector_type(2)));     // NT-capable f32x2

__device__ inline float2 cmulf(float2 a, float2 b) {
    return make_float2(a.x * b.x - a.y * b.y, a.x * b.y + a.y * b.x);
}
__device__ inline float2 cadd(float2 a, float2 b) { return make_float2(a.x + b.x, a.y + b.y); }
__device__ inline float2 csub(float2 a, float2 b) { return make_float2(a.x - b.x, a.y - b.y); }

// bf16 pair pack via HW cvt (RNE): D[15:0]=bf16(x), D[31:16]=bf16(y).
__device__ inline unsigned pack_c(float2 v) {
    unsigned r;
    asm("v_cvt_pk_bf16_f32 %0, %1, %2" : "=v"(r) : "v"(v.x), "v"(v.y));
    return r;
}
__device__ inline float2 unpack_c(unsigned u) {
    return make_float2(__uint_as_float(u << 16), __uint_as_float(u & 0xffff0000u));
}

// Fast 8-point DFT, radix-2 DIT. DIR = -1 forward, +1 inverse. ~56 real ops.
template <int DIR>
__device__ inline float2 jmul(float2 z) {  // DIR*i * z
    return (DIR < 0) ? make_float2(z.y, -z.x) : make_float2(-z.y, z.x);
}
template <int DIR>
__device__ inline void dft8(const float2 v[8], float2 y[8]) {
    const float s = 0.70710678118654752440f;
    float2 a0 = cadd(v[0], v[4]), a1 = csub(v[0], v[4]);
    float2 a2 = cadd(v[2], v[6]), a3 = csub(v[2], v[6]);
    float2 A0 = cadd(a0, a2), A2 = csub(a0, a2);
    float2 tj = jmul<DIR>(a3);
    float2 A1 = cadd(a1, tj), A3 = csub(a1, tj);
    float2 b0 = cadd(v[1], v[5]), b1 = csub(v[1], v[5]);
    float2 b2 = cadd(v[3], v[7]), b3 = csub(v[3], v[7]);
    float2 B0 = cadd(b0, b2), B2 = csub(b0, b2);
    float2 uj = jmul<DIR>(b3);
    float2 B1 = cadd(b1, uj), B3 = csub(b1, uj);
    float2 W1B1 = (DIR < 0) ? make_float2(s * (B1.x + B1.y), s * (B1.y - B1.x))
                            : make_float2(s * (B1.x - B1.y), s * (B1.x + B1.y));
    float2 W2B2 = jmul<DIR>(B2);
    float2 W3B3 = (DIR < 0) ? make_float2(s * (B3.y - B3.x), -s * (B3.x + B3.y))
                            : make_float2(-s * (B3.x + B3.y), s * (B3.x - B3.y));
    y[0] = cadd(A0, B0);   y[4] = csub(A0, B0);
    y[1] = cadd(A1, W1B1); y[5] = csub(A1, W1B1);
    y[2] = cadd(A2, W2B2); y[6] = csub(A2, W2B2);
    y[3] = cadd(A3, W3B3); y[7] = csub(A3, W3B3);
}

// Per-thread twiddles for its p = t&7: tw[k1-1] = (cos, sin)(+2*pi*p*k1/64)
__device__ inline void make_tw(int p, float2 tw[7]) {
#pragma unroll
    for (int k1 = 1; k1 < 8; k1++) {
        float ang = TWO_PI_64 * (float)(p * k1);
        float sn, cs;
        __sincosf(ang, &sn, &cs);
        tw[k1 - 1] = make_float2(cs, sn);
    }
}

// 64-pt FFT on 64 contiguous float2 in LDS, cooperatively by 8 threads p=0..7
// (lanes 8r..8r+7 of ONE wave: wave-synchronous, no block barriers).
template <int DIR>
__device__ inline void fft64_lds(float2* base, int p, const float2 tw[7]) {
    float2 v[8], a[8];
#pragma unroll
    for (int n1 = 0; n1 < 8; n1++) v[n1] = base[8 * n1 + p];
    dft8<DIR>(v, a);
#pragma unroll
    for (int k1 = 1; k1 < 8; k1++) {
        float2 w = make_float2(tw[k1 - 1].x, (float)DIR * tw[k1 - 1].y);
        a[k1] = cmulf(a[k1], w);
    }
#pragma unroll
    for (int k1 = 0; k1 < 8; k1++) base[8 * k1 + p] = a[k1];
    __builtin_amdgcn_wave_barrier();
    float2 u[8], y[8];
#pragma unroll
    for (int n2 = 0; n2 < 8; n2++) u[n2] = base[8 * p + n2];
    dft8<DIR>(u, y);
    __builtin_amdgcn_wave_barrier();
#pragma unroll
    for (int k2 = 0; k2 < 8; k2++) base[8 * k2 + p] = y[k2];
}

// ---------------- Setup: build MFMA weight fragments + biases into d_ws tail.
__global__ __launch_bounds__(256) void k_wfrag(const float* __restrict__ w1,
                                               const float* __restrict__ b1,
                                               const float* __restrict__ w2,
                                               const float* __restrict__ b2,
                                               uint4* __restrict__ WFg,
                                               float* __restrict__ BIASg) {
    const int t = threadIdx.x;
    const int widx = blockIdx.x * 256 + t;  // 0..2047
    const int lane = widx & 63;
    const int half = (widx >> 6) & 1;   // 0: real-out cols, 1: imag-out cols
    const float* ws = (widx & 128) ? w2 : w1;
    const int blk = widx >> 8;
    const int n = lane & 15;
    const int kc = lane >> 4;
    unsigned wrd[4];
#pragma unroll
    for (int j2 = 0; j2 < 4; j2++) {
        float v[2];
#pragma unroll
        for (int e = 0; e < 2; e++) {
            const int k = kc * 8 + j2 * 2 + e;
            float val;
            if (k < 16)
                val = half ? ws[2048 + blk * 256 + k * 16 + n]
                           : ws[blk * 256 + k * 16 + n];
            else
                val = half ? ws[blk * 256 + (k - 16) * 16 + n]
                           : -ws[2048 + blk * 256 + (k - 16) * 16 + n];
            v[e] = val;
        }
        wrd[j2] = pack_c(make_float2(v[0], v[1]));
    }
    WFg[widx] = make_uint4(wrd[0], wrd[1], wrd[2], wrd[3]);
    if (blockIdx.x == 0) {
        BIASg[t] = b1[t];
        BIASg[256 + t] = b2[t];
    }
}

// ---------------- Pass 1: rfft along W, two real channels packed per complex
// FFT. x f32 -> buf (b,d,h,wr,c) packed bf16. x loads are non-temporal
// (streaming, zero reuse) so they don't evict the L3-resident spectrum.
__global__ __launch_bounds__(256) void k_rfft_w(const float* __restrict__ x,
                                                unsigned* __restrict__ buf) {
    __shared__ float2 lds[32 * LROW];
    const int t = threadIdx.x;
    const size_t bdh = blockIdx.x;
    const float* xp = x + bdh * (size_t)(NDIM * CC);
    unsigned* op = buf + bdh * (size_t)(WR * CC);
    float2 tw[7];
    make_tw(t & 7, tw);
    for (int chunk = 0; chunk < 2; chunk++) {
        const int c0 = chunk * 64;  // 32 channel-pairs per chunk
#pragma unroll
        for (int k8 = 0; k8 < 8; k8++) {
            int idx = k8 * 256 + t;
            int p = idx & 31, w = idx >> 5;
            f32x2n v = __builtin_nontemporal_load(
                (const f32x2n*)&xp[(size_t)w * CC + c0 + 2 * p]);
            lds[p * LROW + w] = make_float2(v.x * ORTHO, v.y * ORTHO);
        }
        __syncthreads();
        fft64_lds<-1>(&lds[(t >> 3) * LROW], t & 7, tw);
        __syncthreads();
        // untangle: Xa = (Z[k]+conj(Z[m]))/2, Xb = -i(Z[k]-conj(Z[m]))/2, m=64-k
        for (int i = t; i < WR * 32; i += 256) {
            int p = i & 31, k = i >> 5;
            int m = (64 - k) & 63;
            float2 Z1 = lds[p * LROW + k];
            float2 Z2 = lds[p * LROW + m];
            float2 Xa = make_float2(0.5f * (Z1.x + Z2.x), 0.5f * (Z1.y - Z2.y));
            float2 Xb = make_float2(0.5f * (Z1.y + Z2.y), 0.5f * (Z2.x - Z1.x));
            uint2 u = make_uint2(pack_c(Xa), pack_c(Xb));
            *(uint2*)&op[(size_t)k * CC + c0 + 2 * p] = u;
        }
        __syncthreads();
    }
}

// ---------------- Passes 2,4: in-place complex FFT along H (coalesced staging).
template <int DIR>
__global__ __launch_bounds__(256) void k_fft_axis(unsigned* __restrict__ buf, int outerB,
                                                  long sA, long sB, long sAxis) {
    __shared__ float2 lds[32 * LROW];
    const int t = threadIdx.x;
    const long a = blockIdx.x / outerB;
    const long ob = blockIdx.x % outerB;
    unsigned* p0 = buf + a * sA + ob * sB;
    float2 tw[7];
    make_tw(t & 7, tw);
    for (int chunk = 0; chunk < 4; chunk++) {
        const int c0 = chunk * 32;
#pragma unroll
        for (int k = 0; k < 8; k++) {
            int i = k * 256 + t;
            int c = i & 31, n = i >> 5;
            lds[c * LROW + n] = unpack_c(p0[(long)n * sAxis + c0 + c]);
        }
        __syncthreads();
        fft64_lds<DIR>(&lds[(t >> 3) * LROW], t & 7, tw);
        __syncthreads();
#pragma unroll
        for (int k = 0; k < 8; k++) {
            int i = k * 256 + t;
            int c = i & 31, n = i >> 5;
            p0[(long)n * sAxis + c0 + c] = pack_c(lds[c * LROW + n]);
        }
        __syncthreads();
    }
}

// ---------------- Pass 3 (fused): FFT-D -> MFMA MLP + softshrink -> iFFT-D.
// CTA per (b,h,wr); 4 chunks of [d=64][32 ch] (= 2 MLP blocks each) in f32 LDS.
// Wave wv owns point-columns wv*16..+15 in the MLP phase (reads AND writes) so
// no cross-wave hazard there; FFT phases sync via __syncthreads.
__global__ __launch_bounds__(256) void k_dmlp3(unsigned* __restrict__ buf,
                                               const uint4* __restrict__ WFg,
                                               const float* __restrict__ BIASg) {
    __shared__ float2 lds[32 * LROW];   // 16.9 KB
    __shared__ unsigned SHUF[4 * 272];  // 4.3 KB
    __shared__ float BIAS[512];         // 2 KB
    const int t = threadIdx.x;
    int id = blockIdx.x;
    const int wr = id % WR; id /= WR;
    const int h = id % NDIM; id /= NDIM;
    const int b = id;
    unsigned* p0 = buf + (long)b * S_Bs + (long)h * S_Hs + (long)wr * S_WRs;
    BIAS[t] = BIASg[t];
    BIAS[256 + t] = BIASg[256 + t];
    float2 tw[7];
    make_tw(t & 7, tw);
    const int wv = t >> 6, l = t & 63;
    const int m = l & 15;
    const int kc = l >> 4;
    const int c0m = (kc & 1) * 8;
    const bool imh = kc >= 2;
    unsigned* shuf = &SHUF[wv * 272];

#pragma unroll 1
    for (int ck = 0; ck < 4; ck++) {
        const int c0 = ck * 32;
        // stage (coalesced)
#pragma unroll
        for (int k = 0; k < 8; k++) {
            int i = k * 256 + t;
            int c = i & 31, n = i >> 5;
            lds[c * LROW + n] = unpack_c(p0[(long)n * S_Ds + c0 + c]);
        }
        __syncthreads();
        // forward FFT along d (rows = channels, wave-synchronous)
        fft64_lds<-1>(&lds[(t >> 3) * LROW], t & 7, tw);
        __syncthreads();
        // MFMA MLP on the tile: 2 blocks in this chunk
#pragma unroll 1
        for (int bq = 0; bq < 2; bq++) {
            const int blk = ck * 2 + bq;
            union { unsigned w[4]; bf16x8 v; } A;
#pragma unroll
            for (int j2 = 0; j2 < 4; j2++) {
                float2 va = lds[(bq * 16 + c0m + 2 * j2) * LROW + wv * 16 + m];
                float2 vb = lds[(bq * 16 + c0m + 2 * j2 + 1) * LROW + wv * 16 + m];
                A.w[j2] = imh ? pack_c(make_float2(va.y, vb.y))
                              : pack_c(make_float2(va.x, vb.x));
            }
            union { uint4 q; bf16x8 v; } B1r, B1i, B2r, B2i;
            B1r.q = WFg[(blk * 4 + 0) * 64 + l];
            B1i.q = WFg[(blk * 4 + 1) * 64 + l];
            f32x4v Dr = {0.f, 0.f, 0.f, 0.f}, Di = {0.f, 0.f, 0.f, 0.f};
            Dr = __builtin_amdgcn_mfma_f32_16x16x32_bf16(A.v, B1r.v, Dr, 0, 0, 0);
            Di = __builtin_amdgcn_mfma_f32_16x16x32_bf16(A.v, B1i.v, Di, 0, 0, 0);
            const float b1r_ = BIAS[blk * 16 + m];
            const float b1i_ = BIAS[128 + blk * 16 + m];
#pragma unroll
            for (int r = 0; r < 4; r++) {
                const float o1r = fmaxf(Dr[r] + b1r_, 0.f);
                const float o1i = fmaxf(Di[r] + b1i_, 0.f);
                shuf[(kc * 4 + r) * 17 + m] = pack_c(make_float2(o1r, o1i));
            }
            __builtin_amdgcn_wave_barrier();
            unsigned s[8];
#pragma unroll
            for (int j = 0; j < 8; j++) s[j] = shuf[m * 17 + c0m + j];
            __builtin_amdgcn_wave_barrier();
            union { unsigned w[4]; bf16x8 v; } A2;
            if (!imh) {
                A2.w[0] = (s[0] & 0xffffu) | (s[1] << 16);
                A2.w[1] = (s[2] & 0xffffu) | (s[3] << 16);
                A2.w[2] = (s[4] & 0xffffu) | (s[5] << 16);
                A2.w[3] = (s[6] & 0xffffu) | (s[7] << 16);
            } else {
                A2.w[0] = (s[0] >> 16) | (s[1] & 0xffff0000u);
                A2.w[1] = (s[2] >> 16) | (s[3] & 0xffff0000u);
                A2.w[2] = (s[4] >> 16) | (s[5] & 0xffff0000u);
                A2.w[3] = (s[6] >> 16) | (s[7] & 0xffff0000u);
            }
            B2r.q = WFg[(blk * 4 + 2) * 64 + l];
            B2i.q = WFg[(blk * 4 + 3) * 64 + l];
            f32x4v Er = {0.f, 0.f, 0.f, 0.f}, Ei = {0.f, 0.f, 0.f, 0.f};
            Er = __builtin_amdgcn_mfma_f32_16x16x32_bf16(A2.v, B2r.v, Er, 0, 0, 0);
            Ei = __builtin_amdgcn_mfma_f32_16x16x32_bf16(A2.v, B2i.v, Ei, 0, 0, 0);
            const float b2r_ = BIAS[256 + blk * 16 + m];
            const float b2i_ = BIAS[384 + blk * 16 + m];
#pragma unroll
            for (int r = 0; r < 4; r++) {
                float sr = Er[r] + b2r_, si = Ei[r] + b2i_;
                sr = (sr > LAM) ? (sr - LAM) : ((sr < -LAM) ? (sr + LAM) : 0.f);
                si = (si > LAM) ? (si - LAM) : ((si < -LAM) ? (si + LAM) : 0.f);
                lds[(bq * 16 + m) * LROW + wv * 16 + kc * 4 + r] =
                    make_float2(sr, si);
            }
            __builtin_amdgcn_wave_barrier();
        }
        __syncthreads();
        // inverse FFT along d
        fft64_lds<1>(&lds[(t >> 3) * LROW], t & 7, tw);
        __syncthreads();
        // store (coalesced, packed)
#pragma unroll
        for (int k = 0; k < 8; k++) {
            int i = k * 256 + t;
            int c = i & 31, n = i >> 5;
            p0[(long)n * S_Ds + c0 + c] = pack_c(lds[c * LROW + n]);
        }
        __syncthreads();
    }
}

// ---------------- Pass 5: irfft along W + residual, two channels per inverse
// complex FFT. x loads and out stores are non-temporal (streaming, zero reuse).
__global__ __launch_bounds__(256) void k_irfft_w(const unsigned* __restrict__ buf,
                                                 const float* __restrict__ x,
                                                 float* __restrict__ out) {
    __shared__ float2 lds[32 * LROW];
    const int t = threadIdx.x;
    const size_t bdh = blockIdx.x;
    const unsigned* ip = buf + bdh * (size_t)(WR * CC);
    const float* xp = x + bdh * (size_t)(NDIM * CC);
    float* op = out + bdh * (size_t)(NDIM * CC);
    float2 tw[7];
    make_tw(t & 7, tw);
    for (int chunk = 0; chunk < 2; chunk++) {
        const int c0 = chunk * 64;
        for (int i = t; i < WR * 32; i += 256) {
            int p = i & 31, k = i >> 5;
            uint2 u = *(const uint2*)&ip[(size_t)k * CC + c0 + 2 * p];
            float2 Xa = unpack_c(u.x);
            float2 Xb = unpack_c(u.y);
            if (k == 0 || k == 32) { Xa.y = 0.f; Xb.y = 0.f; }
            lds[p * LROW + k] = make_float2(Xa.x - Xb.y, Xa.y + Xb.x);
            if (k >= 1 && k <= 31)
                lds[p * LROW + (64 - k)] = make_float2(Xa.x + Xb.y, Xb.x - Xa.y);
        }
        __syncthreads();
        fft64_lds<1>(&lds[(t >> 3) * LROW], t & 7, tw);
        __syncthreads();
#pragma unroll
        for (int k8 = 0; k8 < 8; k8++) {
            int idx = k8 * 256 + t;
            int p = idx & 31, w = idx >> 5;
            float2 z = lds[p * LROW + w];
            size_t gi = (size_t)w * CC + c0 + 2 * p;
            f32x2n xv = __builtin_nontemporal_load((const f32x2n*)&xp[gi]);
            f32x2n o;
            o.x = z.x * ORTHO + xv.x;
            o.y = z.y * ORTHO + xv.y;
            __builtin_nontemporal_store(o, (f32x2n*)&op[gi]);
        }
        __syncthreads();
    }
}

extern "C" void kernel_launch(void* const* d_in, const int* in_sizes, int n_in,
                              void* d_out, int out_size, void* d_ws, size_t ws_size,
                              hipStream_t stream) {
    const float* x = (const float*)d_in[0];
    const float* w1 = (const float*)d_in[1];
    const float* b1 = (const float*)d_in[2];
    const float* w2 = (const float*)d_in[3];
    const float* b2 = (const float*)d_in[4];
    float* out = (float*)d_out;
    unsigned* buf = (unsigned*)d_ws;  // B*D*H*WR*C u32 = 138.4 MB (L3-resident)
    uint4* WFg = (uint4*)(buf + WS_FRAG_OFF);
    float* BIASg = (float*)(buf + WS_BIAS_OFF);

    // 0) build MFMA weight fragments + biases (32 KB + 2 KB in d_ws tail)
    k_wfrag<<<8, 256, 0, stream>>>(w1, b1, w2, b2, WFg, BIASg);
    // 1) rfft along W (channel-pair packed, NT x-loads)
    k_rfft_w<<<BB * NDIM * NDIM, 256, 0, stream>>>(x, buf);
    // 2) FFT along H: per (b,d,wr)
    k_fft_axis<-1><<<BB * NDIM * WR, 256, 0, stream>>>(buf, WR, S_Ds, S_WRs, S_Hs);
    // 3) fused FFT-D -> MFMA MLP + softshrink -> iFFT-D: per (b,h,wr)
    k_dmlp3<<<BB * NDIM * WR, 256, 0, stream>>>(buf, WFg, BIASg);
    // 4) inverse FFT along H
    k_fft_axis<1><<<BB * NDIM * WR, 256, 0, stream>>>(buf, WR, S_Ds, S_WRs, S_Hs);
    // 5) irfft along W + residual (channel-pair packed, NT x-loads/out-stores)
    k_irfft_w<<<BB * NDIM * NDIM, 256, 0, stream>>>(buf, x, out);
}